// Round 4
// baseline (216.931 us; speedup 1.0000x reference)
//
#include <hip/hip_runtime.h>
#include <cmath>

#define NPTS 262144
#define NLVL 16
#define NDENSE 5
#define NHASH 11
#define HASH_MASK 0x7FFFFu
#define P2 2654435761u
#define P3 805459861u

typedef float v2f __attribute__((ext_vector_type(2)));
typedef float v4f __attribute__((ext_vector_type(4)));

struct MetaD { float scale[NDENSE]; unsigned off[NDENSE]; unsigned res[NDENSE]; };
struct MetaH { float scale[NHASH]; unsigned off[NHASH]; };

struct Pt { float x, y, z; };
struct Prep { unsigned idx[8]; float fx, fy, fz; };

// NT means load: protects XCD-L2-resident hash tables from the means stream
__device__ __forceinline__ Pt load_pt_nt(const float* __restrict__ means, int p) {
    Pt q;
    q.x = (__builtin_nontemporal_load(means + 3 * p + 0) + 1.0f) * 0.5f;
    q.y = (__builtin_nontemporal_load(means + 3 * p + 1) + 1.0f) * 0.5f;
    q.z = (__builtin_nontemporal_load(means + 3 * p + 2) + 1.0f) * 0.5f;
    return q;
}

// hash index prep (hsize = 2^19) — off folded into idx; branch-free
__device__ __forceinline__ Prep hprep(Pt q, float s, unsigned off) {
    const float px = q.x * s, py = q.y * s, pz = q.z * s;
    const float gx = floorf(px), gy = floorf(py), gz = floorf(pz);
    Prep d;
    d.fx = px - gx; d.fy = py - gy; d.fz = pz - gz;
    const unsigned ix = (unsigned)gx, iy = (unsigned)gy, iz = (unsigned)gz;
    const unsigned hy0 = iy * P2, hy1 = hy0 + P2;
    const unsigned hz0 = iz * P3, hz1 = hz0 + P3;
    const unsigned h0 = hy0 ^ hz0, h1 = hy1 ^ hz0, h2 = hy0 ^ hz1, h3 = hy1 ^ hz1;
    d.idx[0] = ((ix ^ h0) & HASH_MASK) + off; d.idx[1] = (((ix + 1u) ^ h0) & HASH_MASK) + off;
    d.idx[2] = ((ix ^ h1) & HASH_MASK) + off; d.idx[3] = (((ix + 1u) ^ h1) & HASH_MASK) + off;
    d.idx[4] = ((ix ^ h2) & HASH_MASK) + off; d.idx[5] = (((ix + 1u) ^ h2) & HASH_MASK) + off;
    d.idx[6] = ((ix ^ h3) & HASH_MASK) + off; d.idx[7] = (((ix + 1u) ^ h3) & HASH_MASK) + off;
    return d;
}

// dense index prep — off folded into idx
__device__ __forceinline__ Prep dprep(Pt q, float s, unsigned r, unsigned off) {
    const float px = q.x * s, py = q.y * s, pz = q.z * s;
    const float gx = floorf(px), gy = floorf(py), gz = floorf(pz);
    Prep d;
    d.fx = px - gx; d.fy = py - gy; d.fz = pz - gz;
    const unsigned dy = r, dz = r * r;
    const unsigned base = (unsigned)gx + (unsigned)gy * dy + (unsigned)gz * dz + off;
    d.idx[0] = base;           d.idx[1] = base + 1;
    d.idx[2] = base + dy;      d.idx[3] = base + dy + 1;
    d.idx[4] = base + dz;      d.idx[5] = base + dz + 1;
    d.idx[6] = base + dz + dy; d.idx[7] = base + dz + dy + 1;
    return d;
}

__device__ __forceinline__ v2f trilerp(const v2f* f, float fx, float fy, float fz) {
    const float wx0 = 1.0f - fx, wy0 = 1.0f - fy, wz0 = 1.0f - fz;
    const float w00 = wz0 * wy0, w01 = wz0 * fy, w10 = fz * wy0, w11 = fz * fy;
    return w00 * (wx0 * f[0] + fx * f[1]) + w01 * (wx0 * f[2] + fx * f[3])
         + w10 * (wx0 * f[4] + fx * f[5]) + w11 * (wx0 * f[6] + fx * f[7]);
}

// ---------------- hash levels 5..15, XCD-affine, 4 points/thread ----------------
// own level (il = xcd): 256 chunks of 1024 pts; shared levels 13..15: 96 chunks/XCD.
// launch_bounds(256,4): VGPR cap 128 so all 32 gathers stay in flight (MLP, not occupancy,
// is the limiter: measured 0.44 req/cy/CU at VGPR=32 vs ~200-deep queue needed).
__global__ __launch_bounds__(256, 4) void enc_hash(
    const float* __restrict__ means, const float* __restrict__ emb,
    v2f* __restrict__ dst, int lvl_major, MetaH meta)
{
    const unsigned b = blockIdx.x;
    const unsigned xcd = b & 7u, slot = b >> 3;
    unsigned il, chunk;
    if (slot < 256u) { il = xcd; chunk = slot; }
    else {
        const unsigned g = xcd * 96u + (slot - 256u);   // 0..767 over levels 13..15
        il = 8u + (g >> 8);
        chunk = g & 255u;
    }
    const float s = meta.scale[il];
    const unsigned off = meta.off[il];
    const unsigned lvl = il + NDENSE;
    const int p0 = (int)(chunk * 1024u + threadIdx.x);
    const v2f* __restrict__ emb2 = (const v2f*)emb;

    Prep P[4];
#pragma unroll
    for (int j = 0; j < 4; ++j)
        P[j] = hprep(load_pt_nt(means, p0 + 256 * j), s, off);

    v2f f[4][8];
#pragma unroll
    for (int j = 0; j < 4; ++j)
#pragma unroll
        for (int k = 0; k < 8; ++k)
            f[j][k] = emb2[P[j].idx[k]];

#pragma unroll
    for (int j = 0; j < 4; ++j) {
        const v2f r = trilerp(f[j], P[j].fx, P[j].fy, P[j].fz);
        const int p = p0 + 256 * j;
        const size_t di = lvl_major ? ((size_t)lvl * NPTS + p) : ((size_t)p * NLVL + lvl);
        dst[di] = r;
    }
}

// ---------------- fallback dense (point-major direct-to-out) ----------------
__global__ __launch_bounds__(256) void enc_dense(
    const float* __restrict__ means, const float* __restrict__ emb,
    v2f* __restrict__ dst, int lvl_major, MetaD meta)
{
    const int p = blockIdx.x * 256 + threadIdx.x;
    const int l = blockIdx.y;

    const float x = (means[3 * p + 0] + 1.0f) * 0.5f;
    const float y = (means[3 * p + 1] + 1.0f) * 0.5f;
    const float z = (means[3 * p + 2] + 1.0f) * 0.5f;

    const float s = meta.scale[l];
    const unsigned off = meta.off[l];
    const unsigned r = meta.res[l];

    const Prep d = dprep(Pt{x, y, z}, s, r, off);
    const v2f* __restrict__ emb2 = (const v2f*)emb;
    v2f f[8];
#pragma unroll
    for (int k = 0; k < 8; ++k) f[k] = emb2[d.idx[k]];

    const v2f res = trilerp(f, d.fx, d.fy, d.fz);
    const size_t di = lvl_major ? ((size_t)l * NPTS + p) : ((size_t)p * NLVL + l);
    dst[di] = res;
}

// ---------------- fused finalize: all 40 dense gathers + 11 ws loads in flight ----------------
__global__ __launch_bounds__(256, 4) void finalize(
    const float* __restrict__ means, const float* __restrict__ emb,
    const v2f* __restrict__ ws, float* __restrict__ out, MetaD meta)
{
    const int p = blockIdx.x * 256 + threadIdx.x;
    const v2f* __restrict__ emb2 = (const v2f*)emb;

    // issue the 11 streaming ws loads first
    v2f h[NHASH];
#pragma unroll
    for (int l = 0; l < NHASH; ++l)
        h[l] = __builtin_nontemporal_load(&ws[(size_t)(NDENSE + l) * NPTS + p]);

    const Pt q = load_pt_nt(means, p);

    // prep all 5 dense levels, then issue all 40 gathers before any use
    Prep P[NDENSE];
#pragma unroll
    for (int l = 0; l < NDENSE; ++l)
        P[l] = dprep(q, meta.scale[l], meta.res[l], meta.off[l]);

    v2f f[NDENSE][8];
#pragma unroll
    for (int l = 0; l < NDENSE; ++l)
#pragma unroll
        for (int k = 0; k < 8; ++k)
            f[l][k] = emb2[P[l].idx[k]];

    v4f o[8];
    v2f* o2 = (v2f*)o;
#pragma unroll
    for (int l = 0; l < NDENSE; ++l)
        o2[l] = trilerp(f[l], P[l].fx, P[l].fy, P[l].fz);
#pragma unroll
    for (int l = 0; l < NHASH; ++l)
        o2[NDENSE + l] = h[l];

    v4f* out4 = (v4f*)(out + (size_t)p * (2 * NLVL));
#pragma unroll
    for (int k = 0; k < 8; ++k)
        __builtin_nontemporal_store(o[k], &out4[k]);
}

extern "C" void kernel_launch(void* const* d_in, const int* in_sizes, int n_in,
                              void* d_out, int out_size, void* d_ws, size_t ws_size,
                              hipStream_t stream)
{
    const float* means = (const float*)d_in[0];
    const float* emb   = (const float*)d_in[1];
    float* out         = (float*)d_out;

    MetaD md;
    MetaH mh;
    const double lg = log2(1.38191288);
    unsigned off = 0;
    for (int l = 0; l < NLVL; ++l) {
        const double scale_d = pow(2.0, (double)l * lg) * 16.0 - 1.0;
        const unsigned res_enc = (unsigned)ceil(scale_d) + 1u;

        const double gres_d = ceil(16.0 * pow(1.38191288, (double)l));
        unsigned long long r3 = (unsigned long long)gres_d;
        r3 = r3 * r3 * r3;
        unsigned long long pl = r3 < (1ull << 19) ? r3 : (1ull << 19);
        pl = (pl + 7ull) / 8ull * 8ull;

        if (l < NDENSE) {
            md.scale[l] = (float)scale_d;
            md.off[l]   = off;
            md.res[l]   = res_enc;
        } else {
            mh.scale[l - NDENSE] = (float)scale_d;
            mh.off[l - NDENSE]   = off;
        }
        off += (unsigned)pl;
    }

    const size_t ws_needed = (size_t)NLVL * NPTS * sizeof(float) * 2;  // 32 MB
    const bool use_ws = ws_size >= ws_needed;

    if (use_ws) {
        v2f* wsp = (v2f*)d_ws;
        enc_hash<<<dim3(8 * 352, 1, 1), 256, 0, stream>>>(means, emb, wsp, 1, mh);
        finalize<<<NPTS / 256, 256, 0, stream>>>(means, emb, (const v2f*)wsp, out, md);
    } else {
        v2f* dst = (v2f*)out;
        enc_dense<<<dim3(NPTS / 256, NDENSE, 1), 256, 0, stream>>>(means, emb, dst, 0, md);
        enc_hash <<<dim3(8 * 352, 1, 1),          256, 0, stream>>>(means, emb, dst, 0, mh);
    }
}